// Round 8
// baseline (999.806 us; speedup 1.0000x reference)
//
#include <hip/hip_runtime.h>

#define VOCAB 50257
#define EMB 256
#define HID 512
#define BATCH 32
#define SEQ 512

typedef _Float16 h2 __attribute__((ext_vector_type(2)));
typedef unsigned int u32;

#if __has_builtin(__builtin_amdgcn_fdot2)
#define FDOT2(a, b, c) __builtin_amdgcn_fdot2((a), (b), (c), false)
#else
static __device__ __forceinline__ float FDOT2(h2 a, h2 b, float c) {
    return c + (float)a.x * (float)b.x + (float)a.y * (float)b.y;
}
#endif

static __device__ __forceinline__ h2 mk2(float a, float b) {
    h2 r; r.x = (_Float16)a; r.y = (_Float16)b; return r;   // RTN converts
}
static __device__ __forceinline__ u32 pk_rtn(float a, float b) {
    return __builtin_bit_cast(u32, mk2(a, b));
}
static __device__ __forceinline__ h2 as_h2(u32 v) {
    return __builtin_bit_cast(h2, v);
}

// ---------------------------------------------------------------------------
// K1: X[tok][j] = bias[j] + emb[ids[tok]] @ Wx[:,j] -> all_h region of d_out.
// ---------------------------------------------------------------------------
__global__ __launch_bounds__(256) void xprec_kernel(
    const int* __restrict__ ids, const float* __restrict__ emb,
    const float* __restrict__ Wx, const float* __restrict__ bias,
    float* __restrict__ allh)
{
    __shared__ float embL[32][EMB];   // 32 KB
    const int tid  = threadIdx.x;
    const int tok0 = blockIdx.x * 32;

    {
        const int t    = tid >> 3;
        const int part = tid & 7;
        const int id   = ids[tok0 + t];
        const float4* src = (const float4*)(emb + (size_t)id * EMB + part * 32);
        float4* dst = (float4*)(&embL[t][part * 32]);
#pragma unroll
        for (int k = 0; k < 8; ++k) dst[k] = src[k];
    }
    __syncthreads();

    const int j0 = tid * 2;
    float2 acc[32];
    const float2 bv = *(const float2*)(bias + j0);
#pragma unroll
    for (int t = 0; t < 32; ++t) acc[t] = bv;

    for (int e = 0; e < EMB; e += 4) {
        const float2 w0 = *(const float2*)(Wx + (size_t)(e + 0) * HID + j0);
        const float2 w1 = *(const float2*)(Wx + (size_t)(e + 1) * HID + j0);
        const float2 w2 = *(const float2*)(Wx + (size_t)(e + 2) * HID + j0);
        const float2 w3 = *(const float2*)(Wx + (size_t)(e + 3) * HID + j0);
#pragma unroll
        for (int t = 0; t < 32; ++t) {
            const float4 ev = *(const float4*)(&embL[t][e]);
            acc[t].x += ev.x * w0.x + ev.y * w1.x + ev.z * w2.x + ev.w * w3.x;
            acc[t].y += ev.x * w0.y + ev.y * w1.y + ev.z * w2.y + ev.w * w3.y;
        }
    }

#pragma unroll
    for (int t = 0; t < 32; ++t) {
        *(float2*)(allh + (size_t)(tok0 + t) * HID + j0) = acc[t];
    }
}

// ---------------------------------------------------------------------------
// K2: one WG per batch, 256 threads = 4 waves, 1 wave/SIMD,
// __launch_bounds__(256,1) -> 512-VGPR budget per wave (no AGPR detour).
// Thread (c=tid&63, p=tid>>6): k-window [128p,128p+128) for 8 cols {64q+c}.
//   q=0..5: 384 h2 in TRUE VGPRs. q=6,7: LDS frag layout, 32 ds_read_b128.
// h: packed h2 in LDS (1 KB); each lane reads ONE h2, the 64 wave-uniform
// operands come from readlane (SGPR operand into v_dot2).
// ---------------------------------------------------------------------------
__global__ __launch_bounds__(256, 1) void rnn_local_kernel(
    const int* __restrict__ mask, const float* __restrict__ Wh,
    float* __restrict__ allh, float* __restrict__ finalh)
{
    __shared__ uint4    wl[2][16][256];  // 128 KB: weight cols q=6,7
    __shared__ float    zp[4][8][64];    // 8 KB: [kwin p][q][c]
    __shared__ _Float16 hF[HID];         // 1 KB packed h
    __shared__ int      mlist[SEQ];      // 2 KB
    __shared__ int      nmL;

    const int tid = threadIdx.x;
    const int b   = blockIdx.x;
    const int c   = tid & 63;
    const int p   = tid >> 6;            // wave id == k-window id == col q for reduce

    // ---- mask compaction (stage mask in zp's storage) ----
    int* maskL = (int*)zp;
    maskL[tid]       = mask[b * SEQ + tid];
    maskL[tid + 256] = mask[b * SEQ + tid + 256];
    __syncthreads();
    if (tid == 0) {
        int n = 0;
        for (int t = 0; t < SEQ; ++t) if (maskL[t]) mlist[n++] = t;
        nmL = n;
    }

    // ---- weights q=0..5 into VGPRs: wq[i] = (Wh[128p+2i][64q+c],
    //      Wh[128p+2i+1][64q+c]), i = 0..63 ----
    const float* wb = Wh + (size_t)(128 * p) * HID + c;
    h2 w0[64], w1[64], w2[64], w3[64], w4[64], w5[64];
#pragma unroll
    for (int i = 0; i < 64; ++i) {
        const float* r0 = wb + (size_t)(2 * i) * HID;
        const float* r1 = r0 + HID;
        w0[i] = mk2(r0[0 * 64], r1[0 * 64]);
        w1[i] = mk2(r0[1 * 64], r1[1 * 64]);
        w2[i] = mk2(r0[2 * 64], r1[2 * 64]);
        w3[i] = mk2(r0[3 * 64], r1[3 * 64]);
        w4[i] = mk2(r0[4 * 64], r1[4 * 64]);
        w5[i] = mk2(r0[5 * 64], r1[5 * 64]);
    }
    // ---- weights q=6,7 into LDS: wl[q][i4][tid].e = k-pair (8*i4+2e) ----
#pragma unroll
    for (int i4 = 0; i4 < 16; ++i4) {
        uint4 v6, v7;
        u32* v6p = (u32*)&v6; u32* v7p = (u32*)&v7;
#pragma unroll
        for (int e = 0; e < 4; ++e) {
            const float* r0 = wb + (size_t)(8 * i4 + 2 * e) * HID;
            const float* r1 = r0 + HID;
            v6p[e] = pk_rtn(r0[6 * 64], r1[6 * 64]);
            v7p[e] = pk_rtn(r0[7 * 64], r1[7 * 64]);
        }
        wl[0][i4][tid] = v6;
        wl[1][i4][tid] = v7;
    }
    __syncthreads();
    const int nm = nmL;

    float* arow = allh + (size_t)b * SEQ * HID;

    // rows before the first masked step carry h = 0
    {
        const int end0 = nm ? mlist[0] : SEQ;
        for (int t = 0; t < end0; ++t) {
            arow[(size_t)t * HID + tid]       = 0.f;
            arow[(size_t)t * HID + tid + 256] = 0.f;
        }
    }

    u32   hpk = 0u;                  // this lane's packed h2 (k-pair 64p + c)
    float hr1 = 0.f, hr2 = 0.f;
    float x1n = 0.f, x2n = 0.f;
    if (nm) {
        x1n = arow[(size_t)mlist[0] * HID + tid];
        x2n = arow[(size_t)mlist[0] * HID + tid + 256];
    }

    for (int it = 0; it < nm; ++it) {
        const int t    = mlist[it];
        const int tend = (it + 1 < nm) ? mlist[it + 1] : SEQ;
        const float x1 = x1n, x2 = x2n;
        if (it + 1 < nm) {           // prefetch next X rows under the matvec
            x1n = arow[(size_t)mlist[it + 1] * HID + tid];
            x2n = arow[(size_t)mlist[it + 1] * HID + tid + 256];
        }

        float a0 = 0.f, a1 = 0.f, a2 = 0.f, a3 = 0.f;
        float a4 = 0.f, a5 = 0.f, a6 = 0.f, a7 = 0.f;
#pragma unroll
        for (int i4 = 0; i4 < 16; ++i4) {
            const uint4 w6 = wl[0][i4][tid];    // ds_read_b128, conflict-free
            const uint4 w7 = wl[1][i4][tid];
            const u32* w6p = (const u32*)&w6;
            const u32* w7p = (const u32*)&w7;
#pragma unroll
            for (int e = 0; e < 4; ++e) {
                const int i = i4 * 4 + e;
                const u32 hu = (u32)__builtin_amdgcn_readlane((int)hpk, i);
                const h2  hv = as_h2(hu);       // SGPR operand
                a0 = FDOT2(w0[i], hv, a0);
                a1 = FDOT2(w1[i], hv, a1);
                a2 = FDOT2(w2[i], hv, a2);
                a3 = FDOT2(w3[i], hv, a3);
                a4 = FDOT2(w4[i], hv, a4);
                a5 = FDOT2(w5[i], hv, a5);
                a6 = FDOT2(as_h2(w6p[e]), hv, a6);
                a7 = FDOT2(as_h2(w7p[e]), hv, a7);
            }
        }
        zp[p][0][c] = a0; zp[p][1][c] = a1; zp[p][2][c] = a2; zp[p][3][c] = a3;
        zp[p][4][c] = a4; zp[p][5][c] = a5; zp[p][6][c] = a6; zp[p][7][c] = a7;
        __syncthreads();

        // thread reduces cols j1 = tid (q=p) and j2 = tid+256 (q=p+4)
        const float z1 = zp[0][p][c] + zp[1][p][c] + zp[2][p][c] + zp[3][p][c];
        const float z2 = zp[0][p + 4][c] + zp[1][p + 4][c]
                       + zp[2][p + 4][c] + zp[3][p + 4][c];
        const float h1 = tanhf(x1 + z1);
        const float hh2 = tanhf(x2 + z2);
        hr1 = h1; hr2 = hh2;
        hF[tid]       = (_Float16)h1;
        hF[tid + 256] = (_Float16)hh2;
        for (int tt = t; tt < tend; ++tt) {      // this step + carried run
            arow[(size_t)tt * HID + tid]       = h1;
            arow[(size_t)tt * HID + tid + 256] = hh2;
        }
        __syncthreads();
        hpk = ((const u32*)hF)[64 * p + c];      // lane's k-pair for next step
    }
    finalh[b * HID + tid]       = hr1;
    finalh[b * HID + tid + 256] = hr2;
}

extern "C" void kernel_launch(void* const* d_in, const int* in_sizes, int n_in,
                              void* d_out, int out_size, void* d_ws, size_t ws_size,
                              hipStream_t stream) {
    const int*   ids  = (const int*)d_in[0];
    const int*   msk  = (const int*)d_in[1];
    const float* emb  = (const float*)d_in[2];
    const float* Wx   = (const float*)d_in[3];
    const float* Wh   = (const float*)d_in[4];
    const float* bias = (const float*)d_in[5];

    float* allh   = (float*)d_out;                              // [B*S][H]
    float* finalh = (float*)d_out + (size_t)BATCH * SEQ * HID;  // [B][H]

    xprec_kernel<<<BATCH * SEQ / 32, 256, 0, stream>>>(ids, emb, Wx, bias, allh);
    rnn_local_kernel<<<BATCH, 256, 0, stream>>>(msk, Wh, allh, finalh);
}

// Round 9
// 675.079 us; speedup vs baseline: 1.4810x; 1.4810x over previous
//
#include <hip/hip_runtime.h>

#define VOCAB 50257
#define EMB 256
#define HID 512
#define BATCH 32
#define SEQ 512

typedef _Float16 h2 __attribute__((ext_vector_type(2)));
typedef unsigned int u32;

#if __has_builtin(__builtin_amdgcn_fdot2)
#define FDOT2(a, b, c) __builtin_amdgcn_fdot2((a), (b), (c), false)
#else
static __device__ __forceinline__ float FDOT2(h2 a, h2 b, float c) {
    return c + (float)a.x * (float)b.x + (float)a.y * (float)b.y;
}
#endif

// lgkm-only barrier: orders LDS traffic WITHOUT draining vmcnt (the full
// __syncthreads drain of outstanding global loads/stores was ~2x900cy/step).
// memory-clobber brackets keep LDS ops from being scheduled across it.
#define LBAR() do {                                            \
    asm volatile("s_waitcnt lgkmcnt(0)" ::: "memory");         \
    __builtin_amdgcn_s_barrier();                              \
    asm volatile("" ::: "memory");                             \
} while (0)

static __device__ __forceinline__ h2 mk2(float a, float b) {
    h2 r; r.x = (_Float16)a; r.y = (_Float16)b; return r;   // RTN converts
}
static __device__ __forceinline__ u32 pk_rtn(float a, float b) {
    return __builtin_bit_cast(u32, mk2(a, b));
}
static __device__ __forceinline__ h2 as_h2(u32 v) {
    return __builtin_bit_cast(h2, v);
}

// ---------------------------------------------------------------------------
// K1: X[tok][j] = bias[j] + emb[ids[tok]] @ Wx[:,j] -> all_h region of d_out.
// ---------------------------------------------------------------------------
__global__ __launch_bounds__(256) void xprec_kernel(
    const int* __restrict__ ids, const float* __restrict__ emb,
    const float* __restrict__ Wx, const float* __restrict__ bias,
    float* __restrict__ allh)
{
    __shared__ float embL[32][EMB];   // 32 KB
    const int tid  = threadIdx.x;
    const int tok0 = blockIdx.x * 32;

    {
        const int t    = tid >> 3;
        const int part = tid & 7;
        const int id   = ids[tok0 + t];
        const float4* src = (const float4*)(emb + (size_t)id * EMB + part * 32);
        float4* dst = (float4*)(&embL[t][part * 32]);
#pragma unroll
        for (int k = 0; k < 8; ++k) dst[k] = src[k];
    }
    __syncthreads();

    const int j0 = tid * 2;
    float2 acc[32];
    const float2 bv = *(const float2*)(bias + j0);
#pragma unroll
    for (int t = 0; t < 32; ++t) acc[t] = bv;

    for (int e = 0; e < EMB; e += 4) {
        const float2 w0 = *(const float2*)(Wx + (size_t)(e + 0) * HID + j0);
        const float2 w1 = *(const float2*)(Wx + (size_t)(e + 1) * HID + j0);
        const float2 w2 = *(const float2*)(Wx + (size_t)(e + 2) * HID + j0);
        const float2 w3 = *(const float2*)(Wx + (size_t)(e + 3) * HID + j0);
#pragma unroll
        for (int t = 0; t < 32; ++t) {
            const float4 ev = *(const float4*)(&embL[t][e]);
            acc[t].x += ev.x * w0.x + ev.y * w1.x + ev.z * w2.x + ev.w * w3.x;
            acc[t].y += ev.x * w0.y + ev.y * w1.y + ev.z * w2.y + ev.w * w3.y;
        }
    }

#pragma unroll
    for (int t = 0; t < 32; ++t) {
        *(float2*)(allh + (size_t)(tok0 + t) * HID + j0) = acc[t];
    }
}

// ---------------------------------------------------------------------------
// K2: one WG per batch (32 WGs, 512 thr = 8 waves), intra-WG sync only.
// Identical structure to R7 EXCEPT the two in-loop barriers are lgkm-only
// (no vmem drain): X prefetch + h stores retire in the background.
// ---------------------------------------------------------------------------
__global__ __launch_bounds__(512, 2) void rnn_local_kernel(
    const int* __restrict__ mask, const float* __restrict__ Wh,
    float* __restrict__ allh, float* __restrict__ finalh)
{
    __shared__ uint4 wl[2][8][512];   // 128 KB: weights q=6,7, frag layout
    __shared__ float zp[8][8][64];    // 16 KB: [kgroup p][q][c] partials
    __shared__ int   mlist[SEQ];      // 2 KB
    __shared__ int   nmL;

    const int tid = threadIdx.x;
    const int b   = blockIdx.x;
    const int c   = tid & 63;
    const int p   = tid >> 6;

    // ---- mask compaction (stage mask in zp's storage; zp unused yet) ----
    int* maskL = (int*)zp;
    maskL[tid] = mask[b * SEQ + tid];
    __syncthreads();
    if (tid == 0) {
        int n = 0;
        for (int t = 0; t < SEQ; ++t) if (maskL[t]) mlist[n++] = t;
        nmL = n;
    }

    // ---- weights q=0..5 into registers ----
    const float* wb = Wh + (size_t)(64 * p) * HID + c;
    h2 wv0[32], wv1[32], wv2[32], wv3[32], wv4[32], wv5[32];
#pragma unroll
    for (int i = 0; i < 32; ++i) {
        const float* r0 = wb + (size_t)(2 * i) * HID;
        const float* r1 = r0 + HID;
        wv0[i] = mk2(r0[0 * 64], r1[0 * 64]);
        wv1[i] = mk2(r0[1 * 64], r1[1 * 64]);
        wv2[i] = mk2(r0[2 * 64], r1[2 * 64]);
        wv3[i] = mk2(r0[3 * 64], r1[3 * 64]);
        wv4[i] = mk2(r0[4 * 64], r1[4 * 64]);
        wv5[i] = mk2(r0[5 * 64], r1[5 * 64]);
    }
    // ---- weights q=6,7 into LDS frag layout ----
#pragma unroll
    for (int blk = 0; blk < 8; ++blk) {
        uint4 v6, v7;
        u32* v6p = (u32*)&v6; u32* v7p = (u32*)&v7;
#pragma unroll
        for (int e = 0; e < 4; ++e) {
            const float* r0 = wb + (size_t)(blk * 8 + 2 * e) * HID;
            const float* r1 = r0 + HID;
            v6p[e] = pk_rtn(r0[6 * 64], r1[6 * 64]);
            v7p[e] = pk_rtn(r0[7 * 64], r1[7 * 64]);
        }
        wl[0][blk][tid] = v6;
        wl[1][blk][tid] = v7;
    }
    __syncthreads();                 // one-time full barrier (setup)
    const int nm = nmL;

    float* arow = allh + (size_t)b * SEQ * HID;

    // rows before the first masked step carry h = 0
    {
        const int end0 = nm ? mlist[0] : SEQ;
        for (int t = 0; t < end0; ++t) arow[(size_t)t * HID + tid] = 0.f;
    }

    u32 hs[32];
#pragma unroll
    for (int i = 0; i < 32; ++i) hs[i] = 0u;

    float hreg  = 0.f;
    float xnext = 0.f;
    if (nm) xnext = arow[(size_t)mlist[0] * HID + tid];

    for (int it = 0; it < nm; ++it) {
        const int t    = mlist[it];
        const int tend = (it + 1 < nm) ? mlist[it + 1] : SEQ;
        const float x  = xnext;
        if (it + 1 < nm)             // prefetch next X row; retires under step
            xnext = arow[(size_t)mlist[it + 1] * HID + tid];

        float a0 = 0.f, a1 = 0.f, a2 = 0.f, a3 = 0.f;
        float a4 = 0.f, a5 = 0.f, a6 = 0.f, a7 = 0.f;
#pragma unroll
        for (int blk = 0; blk < 8; ++blk) {
            const uint4 w6 = wl[0][blk][tid];   // ds_read_b128, conflict-free
            const uint4 w7 = wl[1][blk][tid];
            const u32* w6p = (const u32*)&w6;
            const u32* w7p = (const u32*)&w7;
#pragma unroll
            for (int e = 0; e < 4; ++e) {
                const int i = blk * 4 + e;
                const h2 hv = as_h2(hs[i]);     // wave-uniform operand
                a0 = FDOT2(wv0[i], hv, a0);
                a1 = FDOT2(wv1[i], hv, a1);
                a2 = FDOT2(wv2[i], hv, a2);
                a3 = FDOT2(wv3[i], hv, a3);
                a4 = FDOT2(wv4[i], hv, a4);
                a5 = FDOT2(wv5[i], hv, a5);
                a6 = FDOT2(as_h2(w6p[e]), hv, a6);
                a7 = FDOT2(as_h2(w7p[e]), hv, a7);
            }
        }
        zp[p][0][c] = a0; zp[p][1][c] = a1; zp[p][2][c] = a2; zp[p][3][c] = a3;
        zp[p][4][c] = a4; zp[p][5][c] = a5; zp[p][6][c] = a6; zp[p][7][c] = a7;
        LBAR();                      // lgkm-only: zp writes visible

        // thread tid == column j = p*64+c: reduce 8 partials, tanh
        const float z = zp[0][p][c] + zp[1][p][c] + zp[2][p][c] + zp[3][p][c]
                      + zp[4][p][c] + zp[5][p][c] + zp[6][p][c] + zp[7][p][c];
        const float hn = tanhf(x + z);
        hreg = hn;
        for (int tt = t; tt < tend; ++tt)        // fire-and-forget h stores
            arow[(size_t)tt * HID + tid] = hn;

        // in-wave h redistribution: lanes of wave p hold h[64p + lane]
        const float hpartner = __shfl_xor(hn, 1);
        const u32 pku = pk_rtn(hn, hpartner);    // even lanes: (h[2i],h[2i+1])
#pragma unroll
        for (int i = 0; i < 32; ++i)
            hs[i] = (u32)__builtin_amdgcn_readlane((int)pku, 2 * i);

        LBAR();                      // lgkm-only: zp reads done before reuse
    }
    finalh[b * HID + tid] = hreg;
}

extern "C" void kernel_launch(void* const* d_in, const int* in_sizes, int n_in,
                              void* d_out, int out_size, void* d_ws, size_t ws_size,
                              hipStream_t stream) {
    const int*   ids  = (const int*)d_in[0];
    const int*   msk  = (const int*)d_in[1];
    const float* emb  = (const float*)d_in[2];
    const float* Wx   = (const float*)d_in[3];
    const float* Wh   = (const float*)d_in[4];
    const float* bias = (const float*)d_in[5];

    float* allh   = (float*)d_out;                              // [B*S][H]
    float* finalh = (float*)d_out + (size_t)BATCH * SEQ * HID;  // [B][H]

    xprec_kernel<<<BATCH * SEQ / 32, 256, 0, stream>>>(ids, emb, Wx, bias, allh);
    rnn_local_kernel<<<BATCH, 512, 0, stream>>>(msk, Wh, allh, finalh);
}